// Round 1
// baseline (4020.289 us; speedup 1.0000x reference)
//
#include <hip/hip_runtime.h>
#include <hip/hip_bf16.h>

using bf16 = __hip_bfloat16;
typedef __attribute__((ext_vector_type(8))) short bf16x8;   // 8 bf16 (4 VGPRs)
typedef __attribute__((ext_vector_type(4))) float f32x4;

#define T_DIM 8192
#define DM    4096
#define DFF   14336

#define BM 128
#define BN 128
#define BK 32

// ---------------------------------------------------------------- helpers
__device__ __forceinline__ void gld_lds16(const bf16* gsrc, bf16* ldst) {
  // async global->LDS, 16B per lane; LDS dest is wave-uniform base + lane*16
  auto* g = (const __attribute__((address_space(1))) unsigned int*)gsrc;
  auto* l = (__attribute__((address_space(3))) unsigned int*)ldst;
  __builtin_amdgcn_global_load_lds(g, l, 16, 0, 0);
}

// ---------------------------------------------------------------- fp32 -> bf16 cast
__global__ void cast_bf16_kernel(const float* __restrict__ in,
                                 bf16* __restrict__ out, int n4) {
  int idx = blockIdx.x * blockDim.x + threadIdx.x;
  int stride = gridDim.x * blockDim.x;
  for (int i = idx; i < n4; i += stride) {
    const float4 v = reinterpret_cast<const float4*>(in)[i];
    bf16 t[4] = {__float2bfloat16(v.x), __float2bfloat16(v.y),
                 __float2bfloat16(v.z), __float2bfloat16(v.w)};
    reinterpret_cast<ushort4*>(out)[i] = *reinterpret_cast<ushort4*>(t);
  }
}

// ---------------------------------------------------------------- fp32 [R][C] -> bf16 [C][R]
__global__ void transpose_cast_kernel(const float* __restrict__ in,
                                      bf16* __restrict__ out, int R, int C) {
  __shared__ float tile[32][33];  // +1 pad: no bank conflicts
  const int c0 = blockIdx.x * 32, r0 = blockIdx.y * 32;
  const int tx = threadIdx.x, ty = threadIdx.y;  // block (32,8)
#pragma unroll
  for (int j = 0; j < 4; ++j)
    tile[ty + j * 8][tx] = in[(long)(r0 + ty + j * 8) * C + (c0 + tx)];
  __syncthreads();
#pragma unroll
  for (int j = 0; j < 4; ++j)
    out[(long)(c0 + ty + j * 8) * R + (r0 + tx)] =
        __float2bfloat16(tile[tx][ty + j * 8]);
}

// ---------------------------------------------------------------- GEMM1: gate+up fused, SwiGLU epilogue
// X:[T][DM] bf16, Gt/Ut:[DFF][DM] bf16 (W^T row-major), H:[T][DFF] bf16
__global__ __launch_bounds__(512, 2) void gemm_gateup_kernel(
    const bf16* __restrict__ X, const bf16* __restrict__ Gt,
    const bf16* __restrict__ Ut, bf16* __restrict__ H) {
  __shared__ __align__(16) bf16 sA[2][BM * BK];
  __shared__ __align__(16) bf16 sG[2][BN * BK];
  __shared__ __align__(16) bf16 sU[2][BN * BK];

  const int tid = threadIdx.x;
  const int lane = tid & 63;
  const int wid = tid >> 6;      // 0..7
  const int wm = wid >> 2;       // 0..1  (M)
  const int wn = wid & 3;        // 0..3  (N)
  const int fr = lane & 15;
  const int fg = lane >> 4;

  // bijective XCD swizzle (gridDim.x % 8 == 0)
  const int nwg = gridDim.x;
  const int id = blockIdx.x;
  const int swz = (id & 7) * (nwg >> 3) + (id >> 3);
  const int NBN = DFF / BN;  // 112
  const int bm = swz / NBN, bn = swz % NBN;
  const long row0 = (long)bm * BM, col0 = (long)bn * BN;

  // staging: tid covers tile row tid>>2, k-chunk (tid&3)*8  (16B contiguous)
  const bf16* gA = X + (row0 + (tid >> 2)) * DM + (tid & 3) * 8;
  const bf16* gG = Gt + (col0 + (tid >> 2)) * DM + (tid & 3) * 8;
  const bf16* gU = Ut + (col0 + (tid >> 2)) * DM + (tid & 3) * 8;
  const int ldst = wid * 512;  // wave's 1KB chunk (uniform per wave)

  f32x4 zero = {0.f, 0.f, 0.f, 0.f};
  f32x4 accg[4][2], accu[4][2];
#pragma unroll
  for (int m = 0; m < 4; ++m)
#pragma unroll
    for (int n = 0; n < 2; ++n) { accg[m][n] = zero; accu[m][n] = zero; }

  // prologue
  gld_lds16(gA, &sA[0][ldst]);
  gld_lds16(gG, &sG[0][ldst]);
  gld_lds16(gU, &sU[0][ldst]);
  __syncthreads();

  const int NK = DM / BK;  // 128
  int cur = 0;
  for (int kt = 0; kt < NK; ++kt) {
    if (kt + 1 < NK) {
      const int ko = (kt + 1) * BK;
      gld_lds16(gA + ko, &sA[cur ^ 1][ldst]);
      gld_lds16(gG + ko, &sG[cur ^ 1][ldst]);
      gld_lds16(gU + ko, &sU[cur ^ 1][ldst]);
    }
    bf16x8 a[4], g[2], u[2];
#pragma unroll
    for (int m = 0; m < 4; ++m)
      a[m] = *reinterpret_cast<const bf16x8*>(
          &sA[cur][(wm * 64 + m * 16 + fr) * BK + fg * 8]);
#pragma unroll
    for (int n = 0; n < 2; ++n) {
      g[n] = *reinterpret_cast<const bf16x8*>(
          &sG[cur][(wn * 32 + n * 16 + fr) * BK + fg * 8]);
      u[n] = *reinterpret_cast<const bf16x8*>(
          &sU[cur][(wn * 32 + n * 16 + fr) * BK + fg * 8]);
    }
#pragma unroll
    for (int m = 0; m < 4; ++m)
#pragma unroll
      for (int n = 0; n < 2; ++n) {
        accg[m][n] = __builtin_amdgcn_mfma_f32_16x16x32_bf16(a[m], g[n], accg[m][n], 0, 0, 0);
        accu[m][n] = __builtin_amdgcn_mfma_f32_16x16x32_bf16(a[m], u[n], accu[m][n], 0, 0, 0);
      }
    __syncthreads();
    cur ^= 1;
  }

  // epilogue: H = bf16(silu(gate) * up); C/D: col=lane&15, row=(lane>>4)*4+i
  const long hr0 = row0 + wm * 64;
  const long hc0 = col0 + wn * 32;
#pragma unroll
  for (int m = 0; m < 4; ++m)
#pragma unroll
    for (int n = 0; n < 2; ++n)
#pragma unroll
      for (int i = 0; i < 4; ++i) {
        float gv = accg[m][n][i];
        float uv = accu[m][n][i];
        float hv = (gv / (1.0f + __expf(-gv))) * uv;
        H[(hr0 + m * 16 + fg * 4 + i) * DFF + (hc0 + n * 16 + fr)] =
            __float2bfloat16(hv);
      }
}

// ---------------------------------------------------------------- GEMM2: out = routing * (H @ Wd)
// A:[T][DFF] bf16, Bt:[DM][DFF] bf16 (Wd^T row-major), out:[T][DM] fp32
__global__ __launch_bounds__(512, 4) void gemm_down_kernel(
    const bf16* __restrict__ A, const bf16* __restrict__ Bt,
    const float* __restrict__ routing, float* __restrict__ out) {
  __shared__ __align__(16) bf16 sA[2][BM * BK];
  __shared__ __align__(16) bf16 sB[2][BN * BK];

  const int tid = threadIdx.x;
  const int lane = tid & 63;
  const int wid = tid >> 6;
  const int wm = wid >> 2;
  const int wn = wid & 3;
  const int fr = lane & 15;
  const int fg = lane >> 4;

  const int nwg = gridDim.x;
  const int id = blockIdx.x;
  const int swz = (id & 7) * (nwg >> 3) + (id >> 3);
  const int NBN = DM / BN;  // 32
  const int bm = swz / NBN, bn = swz % NBN;
  const long row0 = (long)bm * BM, col0 = (long)bn * BN;

  const bf16* gA = A + (row0 + (tid >> 2)) * DFF + (tid & 3) * 8;
  const bf16* gB = Bt + (col0 + (tid >> 2)) * DFF + (tid & 3) * 8;
  const int ldst = wid * 512;

  f32x4 zero = {0.f, 0.f, 0.f, 0.f};
  f32x4 acc[4][2];
#pragma unroll
  for (int m = 0; m < 4; ++m)
#pragma unroll
    for (int n = 0; n < 2; ++n) acc[m][n] = zero;

  gld_lds16(gA, &sA[0][ldst]);
  gld_lds16(gB, &sB[0][ldst]);
  __syncthreads();

  const int NK = DFF / BK;  // 448
  int cur = 0;
  for (int kt = 0; kt < NK; ++kt) {
    if (kt + 1 < NK) {
      const int ko = (kt + 1) * BK;
      gld_lds16(gA + ko, &sA[cur ^ 1][ldst]);
      gld_lds16(gB + ko, &sB[cur ^ 1][ldst]);
    }
    bf16x8 a[4], b[2];
#pragma unroll
    for (int m = 0; m < 4; ++m)
      a[m] = *reinterpret_cast<const bf16x8*>(
          &sA[cur][(wm * 64 + m * 16 + fr) * BK + fg * 8]);
#pragma unroll
    for (int n = 0; n < 2; ++n)
      b[n] = *reinterpret_cast<const bf16x8*>(
          &sB[cur][(wn * 32 + n * 16 + fr) * BK + fg * 8]);
#pragma unroll
    for (int m = 0; m < 4; ++m)
#pragma unroll
      for (int n = 0; n < 2; ++n)
        acc[m][n] = __builtin_amdgcn_mfma_f32_16x16x32_bf16(a[m], b[n], acc[m][n], 0, 0, 0);
    __syncthreads();
    cur ^= 1;
  }

  const long r0w = row0 + wm * 64;
  const long c0w = col0 + wn * 32;
#pragma unroll
  for (int m = 0; m < 4; ++m)
#pragma unroll
    for (int i = 0; i < 4; ++i) {
      const long r = r0w + m * 16 + fg * 4 + i;
      const float rv = routing[r];
#pragma unroll
      for (int n = 0; n < 2; ++n)
        out[r * DM + (c0w + n * 16 + fr)] = rv * acc[m][n][i];
    }
}

// ---------------------------------------------------------------- launch
extern "C" void kernel_launch(void* const* d_in, const int* in_sizes, int n_in,
                              void* d_out, int out_size, void* d_ws, size_t ws_size,
                              hipStream_t stream) {
  const float* X  = (const float*)d_in[0];
  const float* rw = (const float*)d_in[1];
  const float* Wg = (const float*)d_in[2];
  const float* Wu = (const float*)d_in[3];
  const float* Wd = (const float*)d_in[4];
  float* out = (float*)d_out;

  char* ws = (char*)d_ws;
  size_t off = 0;
  bf16* Xb = (bf16*)(ws + off); off += (size_t)T_DIM * DM * 2;   // 64 MiB
  bf16* GT = (bf16*)(ws + off); off += (size_t)DM * DFF * 2;     // 112 MiB
  bf16* UT = (bf16*)(ws + off); off += (size_t)DM * DFF * 2;     // 112 MiB
  bf16* DT = (bf16*)(ws + off); off += (size_t)DM * DFF * 2;     // 112 MiB
  bf16* Hb = (bf16*)(ws + off); off += (size_t)T_DIM * DFF * 2;  // 224 MiB

  cast_bf16_kernel<<<2048, 256, 0, stream>>>(X, Xb, T_DIM * DM / 4);
  dim3 tpb(32, 8);
  // Wg [DM][DFF] -> GT [DFF][DM]
  transpose_cast_kernel<<<dim3(DFF / 32, DM / 32), tpb, 0, stream>>>(Wg, GT, DM, DFF);
  transpose_cast_kernel<<<dim3(DFF / 32, DM / 32), tpb, 0, stream>>>(Wu, UT, DM, DFF);
  // Wd [DFF][DM] -> DT [DM][DFF]
  transpose_cast_kernel<<<dim3(DM / 32, DFF / 32), tpb, 0, stream>>>(Wd, DT, DFF, DM);

  gemm_gateup_kernel<<<(T_DIM / BM) * (DFF / BN), 512, 0, stream>>>(Xb, GT, UT, Hb);
  gemm_down_kernel<<<(T_DIM / BM) * (DM / BN), 512, 0, stream>>>(Hb, DT, rw, out);
}

// Round 2
// 3416.703 us; speedup vs baseline: 1.1767x; 1.1767x over previous
//
#include <hip/hip_runtime.h>
#include <hip/hip_bf16.h>

using bf16 = __hip_bfloat16;
typedef __attribute__((ext_vector_type(8))) short bf16x8;   // 8 bf16 (4 VGPRs)
typedef __attribute__((ext_vector_type(4))) float f32x4;

#define T_DIM 8192
#define DM    4096
#define DFF   14336

#define MFMA(va, vb, vc) __builtin_amdgcn_mfma_f32_16x16x32_bf16(va, vb, vc, 0, 0, 0)

// ---------------------------------------------------------------- helpers
__device__ __forceinline__ void gld_lds16(const bf16* gsrc, bf16* ldst) {
  auto* g = (const __attribute__((address_space(1))) unsigned int*)gsrc;
  auto* l = (__attribute__((address_space(3))) unsigned int*)ldst;
  __builtin_amdgcn_global_load_lds(g, l, 16, 0, 0);
}

// Stage one 8KB chunk (512 granules of 16B) of a [rows][64] bf16 tile.
// LDS dest is linear (gld_lds requirement); the GLOBAL source is
// inverse-swizzled so reads can apply  addr ^= ((row&7)<<4)  (T2, rule 21).
__device__ __forceinline__ void stage8k(const bf16* __restrict__ gbase, long lda,
                                        long grow0, long k0, bf16* lds_tile,
                                        int gran0, int tid) {
  const int g = gran0 + tid;          // granule index within tile
  const int row = g >> 3, c16 = g & 7;  // 8 granules (128B) per row
  const bf16* src = gbase + (grow0 + row) * lda + k0 + ((long)(c16 ^ (row & 7)) << 3);
  bf16* dst = lds_tile + ((size_t)(gran0 + (tid & ~63)) << 3);  // wave-uniform base
  gld_lds16(src, dst);
}

// Swizzled fragment read: 8 contiguous k (bf16) for MFMA A/B operand.
__device__ __forceinline__ bf16x8 ldsfrag(const bf16* tile, int row, int kk, int fg) {
  int addr = (row << 7) + (kk << 6) + (fg << 4);  // bytes; 128B per row
  addr ^= (row & 7) << 4;                          // T2 XOR swizzle
  return *reinterpret_cast<const bf16x8*>(reinterpret_cast<const char*>(tile) + addr);
}

#define PHASE_MFMA_BEGIN()                            \
  __builtin_amdgcn_s_barrier();                       \
  asm volatile("s_waitcnt lgkmcnt(0)" ::: "memory");  \
  __builtin_amdgcn_sched_barrier(0);                  \
  __builtin_amdgcn_s_setprio(1)

#define PHASE_MFMA_END()                              \
  __builtin_amdgcn_s_setprio(0);                      \
  __builtin_amdgcn_sched_barrier(0);                  \
  __builtin_amdgcn_s_barrier()

// ---------------------------------------------------------------- fp32 -> bf16 cast
__global__ void cast_bf16_kernel(const float* __restrict__ in,
                                 bf16* __restrict__ out, int n4) {
  int idx = blockIdx.x * blockDim.x + threadIdx.x;
  int stride = gridDim.x * blockDim.x;
  for (int i = idx; i < n4; i += stride) {
    const float4 v = reinterpret_cast<const float4*>(in)[i];
    bf16 t[4] = {__float2bfloat16(v.x), __float2bfloat16(v.y),
                 __float2bfloat16(v.z), __float2bfloat16(v.w)};
    reinterpret_cast<ushort4*>(out)[i] = *reinterpret_cast<ushort4*>(t);
  }
}

// ---------------------------------------------------------------- fp32 [R][C] -> bf16 [C][R]
__global__ void transpose_cast_kernel(const float* __restrict__ in,
                                      bf16* __restrict__ out, int R, int C) {
  __shared__ float tile[32][33];
  const int c0 = blockIdx.x * 32, r0 = blockIdx.y * 32;
  const int tx = threadIdx.x, ty = threadIdx.y;  // block (32,8)
#pragma unroll
  for (int j = 0; j < 4; ++j)
    tile[ty + j * 8][tx] = in[(long)(r0 + ty + j * 8) * C + (c0 + tx)];
  __syncthreads();
#pragma unroll
  for (int j = 0; j < 4; ++j)
    out[(long)(c0 + ty + j * 8) * R + (r0 + tx)] =
        __float2bfloat16(tile[tx][ty + j * 8]);
}

// ---------------------------------------------------------------- GEMM1: gate+up fused (8-phase)
// X:[T][DM], Gt/Ut:[DFF][DM] (W^T row-major). Tile 256x128, BK=64, 8 waves.
// Per wave: 128 rows (8 m-frags at m*32+wm*16) x 32 cols (2 n-frags at n*64+wn*16)
// per operand. Phases: {A0+G reads | mh0*G}, {U | mh0*U}, {A1 | mh1*U}, {- | mh1*G}.
__global__ __launch_bounds__(512, 2) void gemm_gateup_kernel(
    const bf16* __restrict__ X, const bf16* __restrict__ Gt,
    const bf16* __restrict__ Ut, bf16* __restrict__ H) {
  __shared__ __align__(16) bf16 sA[2][256 * 64];   // 64 KiB
  __shared__ __align__(16) bf16 sG[2][128 * 64];   // 32 KiB
  __shared__ __align__(16) bf16 sU[2][128 * 64];   // 32 KiB

  const int tid = threadIdx.x;
  const int lane = tid & 63, wid = tid >> 6;
  const int wm = wid >> 2, wn = wid & 3;
  const int fr = lane & 15, fg = lane >> 4;

  const int nwg = gridDim.x, id = blockIdx.x;
  const int swz = (id & 7) * (nwg >> 3) + (id >> 3);
  const int NBN = DFF / 128;  // 112
  const int bm = swz / NBN, bn = swz % NBN;
  const long row0 = (long)bm * 256, col0 = (long)bn * 128;
  const int NK = DM / 64;  // 64 (even: buffer parity preserved under wrap)

  f32x4 accg[8][2], accu[8][2];
  const f32x4 z = {0.f, 0.f, 0.f, 0.f};
#pragma unroll
  for (int m = 0; m < 8; ++m)
#pragma unroll
    for (int n = 0; n < 2; ++n) { accg[m][n] = z; accu[m][n] = z; }

  // prologue: K0 full (A0,A1,G,U), K1 partial (A0,G,U). K1's A1 comes at p1 of t=0.
  stage8k(X, DM, row0, 0, (bf16*)sA[0], 0, tid);
  stage8k(X, DM, row0, 0, (bf16*)sA[0], 512, tid);
  stage8k(X, DM, row0, 0, (bf16*)sA[0], 1024, tid);
  stage8k(X, DM, row0, 0, (bf16*)sA[0], 1536, tid);
  stage8k(Gt, DM, col0, 0, (bf16*)sG[0], 0, tid);
  stage8k(Gt, DM, col0, 0, (bf16*)sG[0], 512, tid);
  stage8k(Ut, DM, col0, 0, (bf16*)sU[0], 0, tid);
  stage8k(Ut, DM, col0, 0, (bf16*)sU[0], 512, tid);
  stage8k(X, DM, row0, 64, (bf16*)sA[1], 0, tid);
  stage8k(X, DM, row0, 64, (bf16*)sA[1], 512, tid);
  stage8k(Gt, DM, col0, 64, (bf16*)sG[1], 0, tid);
  stage8k(Gt, DM, col0, 64, (bf16*)sG[1], 512, tid);
  stage8k(Ut, DM, col0, 64, (bf16*)sU[1], 0, tid);
  stage8k(Ut, DM, col0, 64, (bf16*)sU[1], 512, tid);
  asm volatile("s_waitcnt vmcnt(6)" ::: "memory");  // K0 fully landed; K1's 6 in flight
  __builtin_amdgcn_s_barrier();

  bf16x8 a[4][2], g[2][2], u[2][2];

  for (int t = 0; t < NK; ++t) {
    bf16* aCur = (bf16*)sA[t & 1];
    bf16* gCur = (bf16*)sG[t & 1];
    bf16* uCur = (bf16*)sU[t & 1];
    bf16* aNxt = (bf16*)sA[(t + 1) & 1];
    const long k1 = (long)((t + 1) % NK) * 64;  // wrap: tail stages land harmlessly
    const long k2 = (long)((t + 2) % NK) * 64;

    // ---- phase 1: read A-mh0 (8) + G (4); stage (t+1)A1; MFMA accg[0..3]
#pragma unroll
    for (int m = 0; m < 4; ++m)
#pragma unroll
      for (int kk = 0; kk < 2; ++kk)
        a[m][kk] = ldsfrag(aCur, m * 32 + wm * 16 + fr, kk, fg);
#pragma unroll
    for (int n = 0; n < 2; ++n)
#pragma unroll
      for (int kk = 0; kk < 2; ++kk)
        g[n][kk] = ldsfrag(gCur, n * 64 + wn * 16 + fr, kk, fg);
    stage8k(X, DM, row0, k1, aNxt, 1024, tid);
    stage8k(X, DM, row0, k1, aNxt, 1536, tid);
    PHASE_MFMA_BEGIN();
#pragma unroll
    for (int m = 0; m < 4; ++m)
#pragma unroll
      for (int n = 0; n < 2; ++n)
#pragma unroll
        for (int kk = 0; kk < 2; ++kk)
          accg[m][n] = MFMA(a[m][kk], g[n][kk], accg[m][n]);
    PHASE_MFMA_END();

    // ---- phase 2: read U (4); stage (t+2)A0 (A0 released after p1); MFMA accu[0..3]
#pragma unroll
    for (int n = 0; n < 2; ++n)
#pragma unroll
      for (int kk = 0; kk < 2; ++kk)
        u[n][kk] = ldsfrag(uCur, n * 64 + wn * 16 + fr, kk, fg);
    stage8k(X, DM, row0, k2, aCur, 0, tid);
    stage8k(X, DM, row0, k2, aCur, 512, tid);
    PHASE_MFMA_BEGIN();
#pragma unroll
    for (int m = 0; m < 4; ++m)
#pragma unroll
      for (int n = 0; n < 2; ++n)
#pragma unroll
        for (int kk = 0; kk < 2; ++kk)
          accu[m][n] = MFMA(a[m][kk], u[n][kk], accu[m][n]);
    PHASE_MFMA_END();

    // ---- phase 3: read A-mh1 (8); stage (t+2)G (G released after p1); MFMA accu[4..7]
#pragma unroll
    for (int m = 0; m < 4; ++m)
#pragma unroll
      for (int kk = 0; kk < 2; ++kk)
        a[m][kk] = ldsfrag(aCur, 128 + m * 32 + wm * 16 + fr, kk, fg);
    stage8k(Gt, DM, col0, k2, gCur, 0, tid);
    stage8k(Gt, DM, col0, k2, gCur, 512, tid);
    PHASE_MFMA_BEGIN();
#pragma unroll
    for (int m = 0; m < 4; ++m)
#pragma unroll
      for (int n = 0; n < 2; ++n)
#pragma unroll
        for (int kk = 0; kk < 2; ++kk)
          accu[4 + m][n] = MFMA(a[m][kk], u[n][kk], accu[4 + m][n]);
    PHASE_MFMA_END();

    // ---- phase 4: stage (t+2)U (released after p2); vmcnt(6); MFMA accg[4..7]
    stage8k(Ut, DM, col0, k2, uCur, 0, tid);
    stage8k(Ut, DM, col0, k2, uCur, 512, tid);
    asm volatile("s_waitcnt vmcnt(6)" ::: "memory");  // (t+1) fully staged; newest 6 in flight
    PHASE_MFMA_BEGIN();
#pragma unroll
    for (int m = 0; m < 4; ++m)
#pragma unroll
      for (int n = 0; n < 2; ++n)
#pragma unroll
        for (int kk = 0; kk < 2; ++kk)
          accg[4 + m][n] = MFMA(a[m][kk], g[n][kk], accg[4 + m][n]);
    PHASE_MFMA_END();
  }

  // epilogue: H = bf16(silu(gate) * up)
#pragma unroll
  for (int m = 0; m < 8; ++m) {
    const long r = row0 + m * 32 + wm * 16 + fg * 4;
#pragma unroll
    for (int n = 0; n < 2; ++n) {
      const long cidx = col0 + n * 64 + wn * 16 + fr;
#pragma unroll
      for (int i = 0; i < 4; ++i) {
        float gv = accg[m][n][i];
        float uv = accu[m][n][i];
        float hv = (gv / (1.0f + __expf(-gv))) * uv;
        H[(r + i) * DFF + cidx] = __float2bfloat16(hv);
      }
    }
  }
}

// ---------------------------------------------------------------- GEMM2: out = routing*(H @ Wd)  (8-phase, m201 geometry)
// A:[T][DFF], Bt:[DM][DFF]. Tile 256x256, BK=64, per-wave 128x64, acc[8][4].
__global__ __launch_bounds__(512, 2) void gemm_down_kernel(
    const bf16* __restrict__ A, const bf16* __restrict__ Bt,
    const float* __restrict__ routing, float* __restrict__ out) {
  __shared__ __align__(16) bf16 sA[2][256 * 64];   // 64 KiB
  __shared__ __align__(16) bf16 sB[2][256 * 64];   // 64 KiB

  const int tid = threadIdx.x;
  const int lane = tid & 63, wid = tid >> 6;
  const int wm = wid >> 2, wn = wid & 3;
  const int fr = lane & 15, fg = lane >> 4;

  const int nwg = gridDim.x, id = blockIdx.x;
  const int swz = (id & 7) * (nwg >> 3) + (id >> 3);
  const int NBN = DM / 256;  // 16
  const int bm = swz / NBN, bn = swz % NBN;
  const long row0 = (long)bm * 256, col0 = (long)bn * 256;
  const int NK = DFF / 64;  // 224 (even)

  f32x4 acc[8][4];
  const f32x4 z = {0.f, 0.f, 0.f, 0.f};
#pragma unroll
  for (int m = 0; m < 8; ++m)
#pragma unroll
    for (int n = 0; n < 4; ++n) acc[m][n] = z;

  // prologue: K0 full (A0,A1,B0,B1), K1 partial (A0,B0,B1)
  stage8k(A, DFF, row0, 0, (bf16*)sA[0], 0, tid);
  stage8k(A, DFF, row0, 0, (bf16*)sA[0], 512, tid);
  stage8k(A, DFF, row0, 0, (bf16*)sA[0], 1024, tid);
  stage8k(A, DFF, row0, 0, (bf16*)sA[0], 1536, tid);
  stage8k(Bt, DFF, col0, 0, (bf16*)sB[0], 0, tid);
  stage8k(Bt, DFF, col0, 0, (bf16*)sB[0], 512, tid);
  stage8k(Bt, DFF, col0, 0, (bf16*)sB[0], 1024, tid);
  stage8k(Bt, DFF, col0, 0, (bf16*)sB[0], 1536, tid);
  stage8k(A, DFF, row0, 64, (bf16*)sA[1], 0, tid);
  stage8k(A, DFF, row0, 64, (bf16*)sA[1], 512, tid);
  stage8k(Bt, DFF, col0, 64, (bf16*)sB[1], 0, tid);
  stage8k(Bt, DFF, col0, 64, (bf16*)sB[1], 512, tid);
  stage8k(Bt, DFF, col0, 64, (bf16*)sB[1], 1024, tid);
  stage8k(Bt, DFF, col0, 64, (bf16*)sB[1], 1536, tid);
  asm volatile("s_waitcnt vmcnt(6)" ::: "memory");
  __builtin_amdgcn_s_barrier();

  bf16x8 a[4][2], b[4][2];

  for (int t = 0; t < NK; ++t) {
    bf16* aCur = (bf16*)sA[t & 1];
    bf16* bCur = (bf16*)sB[t & 1];
    bf16* aNxt = (bf16*)sA[(t + 1) & 1];
    const long k1 = (long)((t + 1) % NK) * 64;
    const long k2 = (long)((t + 2) % NK) * 64;

    // ---- phase 1: read A-mh0 (8) + B-nh0 (4); stage (t+1)A1; MFMA Q(mh0,nh0)
#pragma unroll
    for (int m = 0; m < 4; ++m)
#pragma unroll
      for (int kk = 0; kk < 2; ++kk)
        a[m][kk] = ldsfrag(aCur, m * 32 + wm * 16 + fr, kk, fg);
#pragma unroll
    for (int n = 0; n < 2; ++n)
#pragma unroll
      for (int kk = 0; kk < 2; ++kk)
        b[n][kk] = ldsfrag(bCur, n * 64 + wn * 16 + fr, kk, fg);
    stage8k(A, DFF, row0, k1, aNxt, 1024, tid);
    stage8k(A, DFF, row0, k1, aNxt, 1536, tid);
    PHASE_MFMA_BEGIN();
#pragma unroll
    for (int m = 0; m < 4; ++m)
#pragma unroll
      for (int n = 0; n < 2; ++n)
#pragma unroll
        for (int kk = 0; kk < 2; ++kk)
          acc[m][n] = MFMA(a[m][kk], b[n][kk], acc[m][n]);
    PHASE_MFMA_END();

    // ---- phase 2: read B-nh1 (4); stage (t+2)A0; MFMA Q(mh0,nh1)
#pragma unroll
    for (int n = 2; n < 4; ++n)
#pragma unroll
      for (int kk = 0; kk < 2; ++kk)
        b[n][kk] = ldsfrag(bCur, n * 64 + wn * 16 + fr, kk, fg);
    stage8k(A, DFF, row0, k2, aCur, 0, tid);
    stage8k(A, DFF, row0, k2, aCur, 512, tid);
    PHASE_MFMA_BEGIN();
#pragma unroll
    for (int m = 0; m < 4; ++m)
#pragma unroll
      for (int n = 2; n < 4; ++n)
#pragma unroll
        for (int kk = 0; kk < 2; ++kk)
          acc[m][n] = MFMA(a[m][kk], b[n][kk], acc[m][n]);
    PHASE_MFMA_END();

    // ---- phase 3: read A-mh1 (8); stage (t+2)B0; MFMA Q(mh1,nh1)
#pragma unroll
    for (int m = 0; m < 4; ++m)
#pragma unroll
      for (int kk = 0; kk < 2; ++kk)
        a[m][kk] = ldsfrag(aCur, 128 + m * 32 + wm * 16 + fr, kk, fg);
    stage8k(Bt, DFF, col0, k2, bCur, 0, tid);
    stage8k(Bt, DFF, col0, k2, bCur, 512, tid);
    PHASE_MFMA_BEGIN();
#pragma unroll
    for (int m = 0; m < 4; ++m)
#pragma unroll
      for (int n = 2; n < 4; ++n)
#pragma unroll
        for (int kk = 0; kk < 2; ++kk)
          acc[4 + m][n] = MFMA(a[m][kk], b[n][kk], acc[4 + m][n]);
    PHASE_MFMA_END();

    // ---- phase 4: stage (t+2)B1; vmcnt(6); MFMA Q(mh1,nh0)
    stage8k(Bt, DFF, col0, k2, bCur, 1024, tid);
    stage8k(Bt, DFF, col0, k2, bCur, 1536, tid);
    asm volatile("s_waitcnt vmcnt(6)" ::: "memory");
    PHASE_MFMA_BEGIN();
#pragma unroll
    for (int m = 0; m < 4; ++m)
#pragma unroll
      for (int n = 0; n < 2; ++n)
#pragma unroll
        for (int kk = 0; kk < 2; ++kk)
          acc[4 + m][n] = MFMA(a[m][kk], b[n][kk], acc[4 + m][n]);
    PHASE_MFMA_END();
  }

  // epilogue: out = routing[r] * acc
#pragma unroll
  for (int m = 0; m < 8; ++m) {
    const long r0w = row0 + m * 32 + wm * 16 + fg * 4;
#pragma unroll
    for (int i = 0; i < 4; ++i) {
      const long r = r0w + i;
      const float rv = routing[r];
#pragma unroll
      for (int n = 0; n < 4; ++n)
        out[r * DM + (col0 + n * 64 + wn * 16 + fr)] = rv * acc[m][n][i];
    }
  }
}

// ---------------------------------------------------------------- launch
extern "C" void kernel_launch(void* const* d_in, const int* in_sizes, int n_in,
                              void* d_out, int out_size, void* d_ws, size_t ws_size,
                              hipStream_t stream) {
  const float* X  = (const float*)d_in[0];
  const float* rw = (const float*)d_in[1];
  const float* Wg = (const float*)d_in[2];
  const float* Wu = (const float*)d_in[3];
  const float* Wd = (const float*)d_in[4];
  float* out = (float*)d_out;

  char* ws = (char*)d_ws;
  size_t off = 0;
  bf16* Xb = (bf16*)(ws + off); off += (size_t)T_DIM * DM * 2;   // 64 MiB
  bf16* GT = (bf16*)(ws + off); off += (size_t)DM * DFF * 2;     // 112 MiB
  bf16* UT = (bf16*)(ws + off); off += (size_t)DM * DFF * 2;     // 112 MiB
  bf16* DT = (bf16*)(ws + off); off += (size_t)DM * DFF * 2;     // 112 MiB
  bf16* Hb = (bf16*)(ws + off); off += (size_t)T_DIM * DFF * 2;  // 224 MiB

  cast_bf16_kernel<<<2048, 256, 0, stream>>>(X, Xb, T_DIM * DM / 4);
  dim3 tpb(32, 8);
  transpose_cast_kernel<<<dim3(DFF / 32, DM / 32), tpb, 0, stream>>>(Wg, GT, DM, DFF);
  transpose_cast_kernel<<<dim3(DFF / 32, DM / 32), tpb, 0, stream>>>(Wu, UT, DM, DFF);
  transpose_cast_kernel<<<dim3(DM / 32, DFF / 32), tpb, 0, stream>>>(Wd, DT, DFF, DM);

  gemm_gateup_kernel<<<(T_DIM / 256) * (DFF / 128), 512, 0, stream>>>(Xb, GT, UT, Hb);
  gemm_down_kernel<<<(T_DIM / 256) * (DM / 256), 512, 0, stream>>>(Hb, DT, rw, out);
}